// Round 5
// baseline (464.409 us; speedup 1.0000x reference)
//
#include <hip/hip_runtime.h>
#include <hip/hip_bf16.h>
#include <hip/hip_fp16.h>
#include <math.h>

#define N_NODES 50000
#define NFEAT 256
#define NHID 64
#define NHEADS 8
#define FTOT 512
#define E_TOT 1650000
#define ALPHA 0.2f
#define NB_SCAN 196

typedef short s16x4 __attribute__((ext_vector_type(4)));
typedef short s16x8 __attribute__((ext_vector_type(8)));
typedef float f32x4 __attribute__((ext_vector_type(4)));

__device__ __forceinline__ short f2bf(float f) {  // RNE f32->bf16
  unsigned u = __float_as_uint(f);
  unsigned r = u + 0x7fffu + ((u >> 16) & 1u);
  return (short)(r >> 16);
}

__device__ __forceinline__ float att_e(float f1v, float g) {
  float s = f1v + g;
  float lk = (s > 0.f) ? s : ALPHA * s;
  return expf(-lk);
}

__device__ __forceinline__ void fma8(float e, const uint4& u, float* acc) {
  const __half2* hp = reinterpret_cast<const __half2*>(&u);
#pragma unroll
  for (int k = 0; k < 4; ++k) {
    float2 f = __half22float2(hp[k]);
    acc[2 * k] += e * f.x;
    acc[2 * k + 1] += e * f.y;
  }
}

// blocks [0,512): W[h][k][j] fp32 -> Wt[h][j][k] bf16
// blocks [512,...): histogram of src
__global__ __launch_bounds__(256) void setup_kernel(
    const float* __restrict__ W, short* __restrict__ Wt,
    const int* __restrict__ src, int* __restrict__ cnt) {
  int b = blockIdx.x, t = threadIdx.x;
  if (b < 512) {
    int idx = b * 256 + t;
    int h = idx >> 14, r = idx & 16383, k = r >> 6, j = r & 63;
    Wt[h * 16384 + j * 256 + k] = f2bf(W[idx]);
  } else {
    int i = (b - 512) * 256 + t;
    if (i < E_TOT) atomicAdd(&cnt[src[i]], 1);
  }
}

// h1[64 rows x 512 cols] per block via bf16 MFMA. 8 waves, wave w = head w.
// B fragments load direct from L2-resident Wt (no LDS staging).
// Fused epilogue writes f1/f2 (fp32) and h1 (fp16).
__global__ __launch_bounds__(512) void gemm_mfma_kernel(
    const float* __restrict__ x, const short* __restrict__ Wt,
    const float* __restrict__ a, __half* __restrict__ h1,
    float* __restrict__ f1, float* __restrict__ f2) {
  __shared__ __align__(16) short A_s[64 * 40];  // 40-short rows: spread banks
  int bm = blockIdx.x * 64;
  int t = threadIdx.x;
  int wid = t >> 6, l = t & 63;
  int lr = l & 15, lk = l >> 4;
  int arow = t >> 3, acol = (t & 7) * 4;   // stage: 1 float4 per thread
  const short* wbase = Wt + wid * 16384 + lr * 256 + lk * 8;
  f32x4 acc[4][4] = {};
  for (int k0 = 0; k0 < NFEAT; k0 += 32) {
    // stage A: 64 rows x 32 k (fp32 -> bf16), all 512 threads
    {
      int gr = bm + arow;
      s16x4 v = (s16x4)0;
      if (gr < N_NODES) {
        float4 p = *reinterpret_cast<const float4*>(
            x + (size_t)gr * NFEAT + k0 + acol);
        v[0] = f2bf(p.x); v[1] = f2bf(p.y); v[2] = f2bf(p.z); v[3] = f2bf(p.w);
      }
      *reinterpret_cast<s16x4*>(&A_s[arow * 40 + acol]) = v;
    }
    __syncthreads();
    s16x8 bf[4];
#pragma unroll
    for (int nj = 0; nj < 4; ++nj)
      bf[nj] = *reinterpret_cast<const s16x8*>(wbase + nj * 16 * 256 + k0);
    s16x8 af[4];
#pragma unroll
    for (int mi = 0; mi < 4; ++mi)
      af[mi] = *reinterpret_cast<const s16x8*>(&A_s[(mi * 16 + lr) * 40 + lk * 8]);
#pragma unroll
    for (int mi = 0; mi < 4; ++mi)
#pragma unroll
      for (int nj = 0; nj < 4; ++nj)
        acc[mi][nj] = __builtin_amdgcn_mfma_f32_16x16x32_bf16(
            af[mi], bf[nj], acc[mi][nj], 0, 0, 0);
    __syncthreads();
  }
  // store h1 (fp16)
#pragma unroll
  for (int mi = 0; mi < 4; ++mi) {
#pragma unroll
    for (int nj = 0; nj < 4; ++nj) {
#pragma unroll
      for (int q = 0; q < 4; ++q) {
        int r = bm + mi * 16 + lk * 4 + q;
        if (r < N_NODES)
          h1[(size_t)r * FTOT + wid * 64 + nj * 16 + lr] =
              __float2half(acc[mi][nj][q]);
      }
    }
  }
  // fused f1/f2 for head=wid
  float a1v[4], a2v[4];
#pragma unroll
  for (int nj = 0; nj < 4; ++nj) {
    a1v[nj] = a[wid * 128 + nj * 16 + lr];
    a2v[nj] = a[wid * 128 + 64 + nj * 16 + lr];
  }
#pragma unroll
  for (int mi = 0; mi < 4; ++mi) {
#pragma unroll
    for (int q = 0; q < 4; ++q) {
      float p1 = 0.f, p2 = 0.f;
#pragma unroll
      for (int nj = 0; nj < 4; ++nj) {
        p1 += acc[mi][nj][q] * a1v[nj];
        p2 += acc[mi][nj][q] * a2v[nj];
      }
      p1 += __shfl_xor(p1, 1); p2 += __shfl_xor(p2, 1);
      p1 += __shfl_xor(p1, 2); p2 += __shfl_xor(p2, 2);
      p1 += __shfl_xor(p1, 4); p2 += __shfl_xor(p2, 4);
      p1 += __shfl_xor(p1, 8); p2 += __shfl_xor(p2, 8);
      int r = bm + mi * 16 + lk * 4 + q;
      if (lr == 0 && r < N_NODES) {
        f1[r * 8 + wid] = p1;
        f2[r * 8 + wid] = p2;
      }
    }
  }
}

__global__ __launch_bounds__(256) void scan1_kernel(const int* __restrict__ cnt,
                                                    int* __restrict__ offs,
                                                    int* __restrict__ bsum) {
  __shared__ int sh[256];
  int b = blockIdx.x, t = threadIdx.x, i = b * 256 + t;
  int v = (i < N_NODES) ? cnt[i] : 0;
  sh[t] = v;
  __syncthreads();
  for (int o = 1; o < 256; o <<= 1) {
    int u = (t >= o) ? sh[t - o] : 0;
    __syncthreads();
    sh[t] += u;
    __syncthreads();
  }
  if (i < N_NODES) offs[i] = sh[t] - v;
  if (t == 255) bsum[b] = sh[255];
}

__global__ __launch_bounds__(256) void scan2_kernel(int* __restrict__ bsum,
                                                    int* __restrict__ offs) {
  __shared__ int sh[256];
  int t = threadIdx.x;
  int v = (t < NB_SCAN) ? bsum[t] : 0;
  sh[t] = v;
  __syncthreads();
  for (int o = 1; o < 256; o <<= 1) {
    int u = (t >= o) ? sh[t - o] : 0;
    __syncthreads();
    sh[t] += u;
    __syncthreads();
  }
  if (t < NB_SCAN) bsum[t] = sh[t] - v;
  if (t == 255) offs[N_NODES] = sh[255];
}

__global__ __launch_bounds__(256) void scan3_kernel(int* __restrict__ offs,
                                                    const int* __restrict__ bsum) {
  int i = blockIdx.x * 256 + threadIdx.x;
  if (i < N_NODES) offs[i] += bsum[blockIdx.x];
}

__global__ __launch_bounds__(256) void scatter_kernel(
    const int* __restrict__ src, const int* __restrict__ dst,
    const int* __restrict__ offsets, int* __restrict__ fill,
    int* __restrict__ edst) {
  int i = blockIdx.x * 256 + threadIdx.x;
  if (i < E_TOT) {
    int s = src[i];
    int pos = offsets[s] + atomicAdd(&fill[s], 1);
    edst[pos] = dst[i];
  }
}

// one block per node; wave w handles edges beg+w, beg+w+4, ...
// lane l owns features [8l, 8l+8), head = l>>3. Fused e-computation;
// 4-deep explicit gather pipeline.
__global__ __launch_bounds__(256) void aggregate_kernel(
    const __half* __restrict__ h1, const float* __restrict__ f1,
    const float* __restrict__ f2, const int* __restrict__ offsets,
    const int* __restrict__ edst, const float* __restrict__ W_out,
    float* __restrict__ hout) {
  int n = blockIdx.x;
  int wv = threadIdx.x >> 6, l = threadIdx.x & 63;
  int head = l >> 3;
  int beg = offsets[n], end = offsets[n + 1];
  float f1v = f1[n * 8 + head];
  float acc[8] = {};
  float rs = 0.f;
  int j = beg + wv;
  for (; j + 12 < end; j += 16) {
    int d0 = edst[j], d1 = edst[j + 4], d2 = edst[j + 8], d3 = edst[j + 12];
    uint4 u0 = *reinterpret_cast<const uint4*>(h1 + (size_t)d0 * FTOT + l * 8);
    uint4 u1 = *reinterpret_cast<const uint4*>(h1 + (size_t)d1 * FTOT + l * 8);
    uint4 u2 = *reinterpret_cast<const uint4*>(h1 + (size_t)d2 * FTOT + l * 8);
    uint4 u3 = *reinterpret_cast<const uint4*>(h1 + (size_t)d3 * FTOT + l * 8);
    float g0 = f2[d0 * 8 + head];
    float g1 = f2[d1 * 8 + head];
    float g2 = f2[d2 * 8 + head];
    float g3 = f2[d3 * 8 + head];
    float e0 = att_e(f1v, g0), e1 = att_e(f1v, g1);
    float e2 = att_e(f1v, g2), e3 = att_e(f1v, g3);
    rs += (e0 + e1) + (e2 + e3);
    fma8(e0, u0, acc);
    fma8(e1, u1, acc);
    fma8(e2, u2, acc);
    fma8(e3, u3, acc);
  }
  for (; j < end; j += 4) {
    int d = edst[j];
    uint4 u = *reinterpret_cast<const uint4*>(h1 + (size_t)d * FTOT + l * 8);
    float e = att_e(f1v, f2[d * 8 + head]);
    rs += e;
    fma8(e, u, acc);
  }
  __shared__ float sacc[4][FTOT];  // 8 KB
  __shared__ float srs[4][8];
#pragma unroll
  for (int k = 0; k < 8; ++k) sacc[wv][l * 8 + k] = acc[k];
  if ((l & 7) == 0) srs[wv][head] = rs;
  __syncthreads();
  int t = threadIdx.x;
  int hh = t >> 5;  // head of feature 2t
  float a0 = sacc[0][2 * t] + sacc[1][2 * t] + sacc[2][2 * t] + sacc[3][2 * t];
  float a1 = sacc[0][2 * t + 1] + sacc[1][2 * t + 1] + sacc[2][2 * t + 1] +
             sacc[3][2 * t + 1];
  float rsum = srs[0][hh] + srs[1][hh] + srs[2][hh] + srs[3][hh];
  float o0 = a0 / rsum, o1 = a1 / rsum;
  o0 = (o0 > 0.f) ? o0 : expm1f(o0);  // elu (concat=True path)
  o1 = (o1 > 0.f) ? o1 : expm1f(o1);
  float v = o0 * W_out[2 * t] + o1 * W_out[2 * t + 1];
#pragma unroll
  for (int o = 32; o > 0; o >>= 1) v += __shfl_down(v, o);
  __shared__ float red[4];
  if ((t & 63) == 0) red[t >> 6] = v;
  __syncthreads();
  if (t == 0) hout[n] = red[0] + red[1] + red[2] + red[3];
}

// layer-2 edge phase + elu + sigmoid. 4 nodes/block, one wave each.
__global__ __launch_bounds__(256) void layer2_kernel(
    const int* __restrict__ offsets, const int* __restrict__ edst,
    const float* __restrict__ hout, const float* __restrict__ a_out,
    float* __restrict__ out) {
  int n = blockIdx.x * 4 + (threadIdx.x >> 6);
  int l = threadIdx.x & 63;
  float a0 = a_out[0], a1 = a_out[1];
  int beg = offsets[n], end = offsets[n + 1];
  float f1v = hout[n] * a0;
  float rs = 0.f, num = 0.f;
  for (int j = beg + l; j < end; j += 64) {
    int d = edst[j];
    float hd = hout[d];
    float s = f1v + a1 * hd;
    float lk = (s > 0.f) ? s : ALPHA * s;
    float e = expf(-lk);
    rs += e;
    num += e * hd;
  }
#pragma unroll
  for (int o = 32; o > 0; o >>= 1) {
    rs += __shfl_down(rs, o);
    num += __shfl_down(num, o);
  }
  if (l == 0) {
    float o_ = num / rs;
    float el = (o_ > 0.f) ? o_ : expm1f(o_);
    out[n] = 1.f / (1.f + expf(-el));
  }
}

extern "C" void kernel_launch(void* const* d_in, const int* in_sizes, int n_in,
                              void* d_out, int out_size, void* d_ws, size_t ws_size,
                              hipStream_t stream) {
  const float* x = (const float*)d_in[0];
  const int* ei = (const int*)d_in[1];
  const float* W = (const float*)d_in[2];
  const float* a = (const float*)d_in[3];
  const float* W_out = (const float*)d_in[4];
  const float* a_out = (const float*)d_in[5];
  float* out = (float*)d_out;
  const int* src = ei;
  const int* dst = ei + E_TOT;

  char* p = (char*)d_ws;
  auto carve = [&](size_t bytes) {
    char* r = p;
    p += (bytes + 255) & ~(size_t)255;
    return r;
  };
  __half* h1 = (__half*)carve((size_t)N_NODES * FTOT * 2);
  float* f1 = (float*)carve((size_t)N_NODES * 8 * 4);
  float* f2 = (float*)carve((size_t)N_NODES * 8 * 4);
  int* offsets = (int*)carve((size_t)(N_NODES + 1) * 4);
  int* cnt = (int*)carve((size_t)N_NODES * 4);
  int* fill = (int*)carve((size_t)N_NODES * 4);
  int* edst = (int*)carve((size_t)E_TOT * 4);
  int* bsum = (int*)carve((size_t)NB_SCAN * 4);
  short* Wt = (short*)carve((size_t)NHEADS * NFEAT * NHID * 2);
  float* hout = (float*)carve((size_t)N_NODES * 4);

  hipMemsetAsync(cnt, 0, (size_t)N_NODES * 4, stream);
  hipMemsetAsync(fill, 0, (size_t)N_NODES * 4, stream);

  setup_kernel<<<512 + 6446, 256, 0, stream>>>(W, Wt, src, cnt);
  gemm_mfma_kernel<<<782, 512, 0, stream>>>(x, Wt, a, h1, f1, f2);
  scan1_kernel<<<NB_SCAN, 256, 0, stream>>>(cnt, offsets, bsum);
  scan2_kernel<<<1, 256, 0, stream>>>(bsum, offsets);
  scan3_kernel<<<NB_SCAN, 256, 0, stream>>>(offsets, bsum);
  scatter_kernel<<<6446, 256, 0, stream>>>(src, dst, offsets, fill, edst);
  aggregate_kernel<<<N_NODES, 256, 0, stream>>>(h1, f1, f2, offsets, edst, W_out, hout);
  layer2_kernel<<<12500, 256, 0, stream>>>(offsets, edst, hout, a_out, out);
}

// Round 6
// 433.356 us; speedup vs baseline: 1.0717x; 1.0717x over previous
//
#include <hip/hip_runtime.h>
#include <hip/hip_bf16.h>
#include <hip/hip_fp16.h>
#include <math.h>

#define N_NODES 50000
#define NFEAT 256
#define NHID 64
#define NHEADS 8
#define FTOT 512
#define E_TOT 1650000
#define ALPHA 0.2f
#define NB_SCAN 196
#define ALDS 264  // LDS row stride in shorts (256 + 8 pad, keeps 16B align)

typedef short s16x4 __attribute__((ext_vector_type(4)));
typedef short s16x8 __attribute__((ext_vector_type(8)));
typedef float f32x4 __attribute__((ext_vector_type(4)));

__device__ __forceinline__ short f2bf(float f) {  // RNE f32->bf16
  unsigned u = __float_as_uint(f);
  unsigned r = u + 0x7fffu + ((u >> 16) & 1u);
  return (short)(r >> 16);
}

__device__ __forceinline__ float att_e(float f1v, float g) {
  float s = f1v + g;
  float lk = (s > 0.f) ? s : ALPHA * s;
  return expf(-lk);
}

__device__ __forceinline__ void fma8(float e, const uint4& u, float* acc) {
  const __half2* hp = reinterpret_cast<const __half2*>(&u);
#pragma unroll
  for (int k = 0; k < 4; ++k) {
    float2 f = __half22float2(hp[k]);
    acc[2 * k] += e * f.x;
    acc[2 * k + 1] += e * f.y;
  }
}

// blocks [0,512): W[h][k][j] fp32 -> Wt[h][j][k] bf16
// blocks [512,...): histogram of src + per-edge rank (atomicAdd return)
__global__ __launch_bounds__(256) void setup_kernel(
    const float* __restrict__ W, short* __restrict__ Wt,
    const int* __restrict__ src, int* __restrict__ cnt,
    int* __restrict__ rank) {
  int b = blockIdx.x, t = threadIdx.x;
  if (b < 512) {
    int idx = b * 256 + t;
    int h = idx >> 14, r = idx & 16383, k = r >> 6, j = r & 63;
    Wt[h * 16384 + j * 256 + k] = f2bf(W[idx]);
  } else {
    int i = (b - 512) * 256 + t;
    if (i < E_TOT) rank[i] = atomicAdd(&cnt[src[i]], 1);
  }
}

// h1[64 rows x 512 cols] per block via bf16 MFMA. 8 waves, wave w = head w.
// Whole 64x256 A-slice staged to LDS once (ONE barrier); B direct from L2.
// Fused epilogue writes f1/f2 (fp32) and h1 (fp16).
__global__ __launch_bounds__(512) void gemm_mfma_kernel(
    const float* __restrict__ x, const short* __restrict__ Wt,
    const float* __restrict__ a, __half* __restrict__ h1,
    float* __restrict__ f1, float* __restrict__ f2) {
  __shared__ __align__(16) short A_s[64 * ALDS];  // 33 KB
  int bm = blockIdx.x * 64;
  int t = threadIdx.x;
  int wid = t >> 6, l = t & 63;
  int lr = l & 15, lk = l >> 4;
  int arow = t >> 3, acol = (t & 7) * 4;  // thread covers cols acol+32*i
  const short* wbase = Wt + wid * 16384 + lr * 256 + lk * 8;
  int gr = bm + arow;
  // preload entire row slice (8 outstanding HBM loads), convert, store once
  float4 xr[8];
#pragma unroll
  for (int i = 0; i < 8; ++i) {
    if (gr < N_NODES)
      xr[i] = *reinterpret_cast<const float4*>(x + (size_t)gr * NFEAT + i * 32 + acol);
    else
      xr[i] = make_float4(0.f, 0.f, 0.f, 0.f);
  }
#pragma unroll
  for (int i = 0; i < 8; ++i) {
    s16x4 v;
    v[0] = f2bf(xr[i].x); v[1] = f2bf(xr[i].y);
    v[2] = f2bf(xr[i].z); v[3] = f2bf(xr[i].w);
    *reinterpret_cast<s16x4*>(&A_s[arow * ALDS + i * 32 + acol]) = v;
  }
  __syncthreads();
  f32x4 acc[4][4] = {};
  for (int k0 = 0; k0 < NFEAT; k0 += 32) {
    s16x8 bf[4];
#pragma unroll
    for (int nj = 0; nj < 4; ++nj)
      bf[nj] = *reinterpret_cast<const s16x8*>(wbase + nj * 16 * 256 + k0);
    s16x8 af[4];
#pragma unroll
    for (int mi = 0; mi < 4; ++mi)
      af[mi] = *reinterpret_cast<const s16x8*>(
          &A_s[(mi * 16 + lr) * ALDS + k0 + lk * 8]);
#pragma unroll
    for (int mi = 0; mi < 4; ++mi)
#pragma unroll
      for (int nj = 0; nj < 4; ++nj)
        acc[mi][nj] = __builtin_amdgcn_mfma_f32_16x16x32_bf16(
            af[mi], bf[nj], acc[mi][nj], 0, 0, 0);
  }
  // store h1 (fp16)
#pragma unroll
  for (int mi = 0; mi < 4; ++mi) {
#pragma unroll
    for (int nj = 0; nj < 4; ++nj) {
#pragma unroll
      for (int q = 0; q < 4; ++q) {
        int r = bm + mi * 16 + lk * 4 + q;
        if (r < N_NODES)
          h1[(size_t)r * FTOT + wid * 64 + nj * 16 + lr] =
              __float2half(acc[mi][nj][q]);
      }
    }
  }
  // fused f1/f2 for head=wid
  float a1v[4], a2v[4];
#pragma unroll
  for (int nj = 0; nj < 4; ++nj) {
    a1v[nj] = a[wid * 128 + nj * 16 + lr];
    a2v[nj] = a[wid * 128 + 64 + nj * 16 + lr];
  }
#pragma unroll
  for (int mi = 0; mi < 4; ++mi) {
#pragma unroll
    for (int q = 0; q < 4; ++q) {
      float p1 = 0.f, p2 = 0.f;
#pragma unroll
      for (int nj = 0; nj < 4; ++nj) {
        p1 += acc[mi][nj][q] * a1v[nj];
        p2 += acc[mi][nj][q] * a2v[nj];
      }
      p1 += __shfl_xor(p1, 1); p2 += __shfl_xor(p2, 1);
      p1 += __shfl_xor(p1, 2); p2 += __shfl_xor(p2, 2);
      p1 += __shfl_xor(p1, 4); p2 += __shfl_xor(p2, 4);
      p1 += __shfl_xor(p1, 8); p2 += __shfl_xor(p2, 8);
      int r = bm + mi * 16 + lk * 4 + q;
      if (lr == 0 && r < N_NODES) {
        f1[r * 8 + wid] = p1;
        f2[r * 8 + wid] = p2;
      }
    }
  }
}

__global__ __launch_bounds__(256) void scan1_kernel(const int* __restrict__ cnt,
                                                    int* __restrict__ offs,
                                                    int* __restrict__ bsum) {
  __shared__ int sh[256];
  int b = blockIdx.x, t = threadIdx.x, i = b * 256 + t;
  int v = (i < N_NODES) ? cnt[i] : 0;
  sh[t] = v;
  __syncthreads();
  for (int o = 1; o < 256; o <<= 1) {
    int u = (t >= o) ? sh[t - o] : 0;
    __syncthreads();
    sh[t] += u;
    __syncthreads();
  }
  if (i < N_NODES) offs[i] = sh[t] - v;
  if (t == 255) bsum[b] = sh[255];
}

__global__ __launch_bounds__(256) void scan2_kernel(int* __restrict__ bsum,
                                                    int* __restrict__ offs) {
  __shared__ int sh[256];
  int t = threadIdx.x;
  int v = (t < NB_SCAN) ? bsum[t] : 0;
  sh[t] = v;
  __syncthreads();
  for (int o = 1; o < 256; o <<= 1) {
    int u = (t >= o) ? sh[t - o] : 0;
    __syncthreads();
    sh[t] += u;
    __syncthreads();
  }
  if (t < NB_SCAN) bsum[t] = sh[t] - v;
  if (t == 255) offs[N_NODES] = sh[255];
}

__global__ __launch_bounds__(256) void scan3_kernel(int* __restrict__ offs,
                                                    const int* __restrict__ bsum) {
  int i = blockIdx.x * 256 + threadIdx.x;
  if (i < N_NODES) offs[i] += bsum[blockIdx.x];
}

// edst[offsets[s] + rank[i]] = dst[i]  (no atomics)
__global__ __launch_bounds__(256) void scatter_kernel(
    const int* __restrict__ src, const int* __restrict__ dst,
    const int* __restrict__ offsets, const int* __restrict__ rank,
    int* __restrict__ edst) {
  int i = blockIdx.x * 256 + threadIdx.x;
  if (i < E_TOT) {
    int s = src[i];
    edst[offsets[s] + rank[i]] = dst[i];
  }
}

// one block per node. Wave wv owns contiguous chunks [beg+wv*8+32k, +8):
// 8-deep gather pipeline (8 h1-rows + 8 f2 in flight per wave).
// lane l owns features [8l, 8l+8), head = l>>3.
__global__ __launch_bounds__(256) void aggregate_kernel(
    const __half* __restrict__ h1, const float* __restrict__ f1,
    const float* __restrict__ f2, const int* __restrict__ offsets,
    const int* __restrict__ edst, const float* __restrict__ W_out,
    float* __restrict__ hout) {
  int n = blockIdx.x;
  int wv = threadIdx.x >> 6, l = threadIdx.x & 63;
  int head = l >> 3;
  int beg = offsets[n], end = offsets[n + 1];
  float f1v = f1[n * 8 + head];
  float acc[8] = {};
  float rs = 0.f;
  int j = beg + wv * 8;
  for (; j + 7 < end; j += 32) {
    int dd[8];
#pragma unroll
    for (int k = 0; k < 8; ++k) dd[k] = edst[j + k];
    uint4 uu[8];
#pragma unroll
    for (int k = 0; k < 8; ++k)
      uu[k] = *reinterpret_cast<const uint4*>(h1 + (size_t)dd[k] * FTOT + l * 8);
    float gg[8];
#pragma unroll
    for (int k = 0; k < 8; ++k) gg[k] = f2[dd[k] * 8 + head];
#pragma unroll
    for (int k = 0; k < 8; ++k) {
      float e = att_e(f1v, gg[k]);
      rs += e;
      fma8(e, uu[k], acc);
    }
  }
  // this wave's final (partial) chunk
  int e8 = (j + 8 < end) ? (j + 8) : end;
  for (; j < e8; ++j) {
    int d = edst[j];
    uint4 u = *reinterpret_cast<const uint4*>(h1 + (size_t)d * FTOT + l * 8);
    float e = att_e(f1v, f2[d * 8 + head]);
    rs += e;
    fma8(e, u, acc);
  }
  __shared__ float sacc[4][FTOT];  // 8 KB
  __shared__ float srs[4][8];
#pragma unroll
  for (int k = 0; k < 8; ++k) sacc[wv][l * 8 + k] = acc[k];
  if ((l & 7) == 0) srs[wv][head] = rs;
  __syncthreads();
  int t = threadIdx.x;
  int hh = t >> 5;  // head of feature 2t
  float a0 = sacc[0][2 * t] + sacc[1][2 * t] + sacc[2][2 * t] + sacc[3][2 * t];
  float a1 = sacc[0][2 * t + 1] + sacc[1][2 * t + 1] + sacc[2][2 * t + 1] +
             sacc[3][2 * t + 1];
  float rsum = srs[0][hh] + srs[1][hh] + srs[2][hh] + srs[3][hh];
  float o0 = a0 / rsum, o1 = a1 / rsum;
  o0 = (o0 > 0.f) ? o0 : expm1f(o0);  // elu (concat=True path)
  o1 = (o1 > 0.f) ? o1 : expm1f(o1);
  float v = o0 * W_out[2 * t] + o1 * W_out[2 * t + 1];
#pragma unroll
  for (int o = 32; o > 0; o >>= 1) v += __shfl_down(v, o);
  __shared__ float red[4];
  if ((t & 63) == 0) red[t >> 6] = v;
  __syncthreads();
  if (t == 0) hout[n] = red[0] + red[1] + red[2] + red[3];
}

// layer-2 edge phase + elu + sigmoid. 4 nodes/block, one wave each.
__global__ __launch_bounds__(256) void layer2_kernel(
    const int* __restrict__ offsets, const int* __restrict__ edst,
    const float* __restrict__ hout, const float* __restrict__ a_out,
    float* __restrict__ out) {
  int n = blockIdx.x * 4 + (threadIdx.x >> 6);
  int l = threadIdx.x & 63;
  float a0 = a_out[0], a1 = a_out[1];
  int beg = offsets[n], end = offsets[n + 1];
  float f1v = hout[n] * a0;
  float rs = 0.f, num = 0.f;
  for (int j = beg + l; j < end; j += 64) {
    int d = edst[j];
    float hd = hout[d];
    float s = f1v + a1 * hd;
    float lk = (s > 0.f) ? s : ALPHA * s;
    float e = expf(-lk);
    rs += e;
    num += e * hd;
  }
#pragma unroll
  for (int o = 32; o > 0; o >>= 1) {
    rs += __shfl_down(rs, o);
    num += __shfl_down(num, o);
  }
  if (l == 0) {
    float o_ = num / rs;
    float el = (o_ > 0.f) ? o_ : expm1f(o_);
    out[n] = 1.f / (1.f + expf(-el));
  }
}

extern "C" void kernel_launch(void* const* d_in, const int* in_sizes, int n_in,
                              void* d_out, int out_size, void* d_ws, size_t ws_size,
                              hipStream_t stream) {
  const float* x = (const float*)d_in[0];
  const int* ei = (const int*)d_in[1];
  const float* W = (const float*)d_in[2];
  const float* a = (const float*)d_in[3];
  const float* W_out = (const float*)d_in[4];
  const float* a_out = (const float*)d_in[5];
  float* out = (float*)d_out;
  const int* src = ei;
  const int* dst = ei + E_TOT;

  char* p = (char*)d_ws;
  auto carve = [&](size_t bytes) {
    char* r = p;
    p += (bytes + 255) & ~(size_t)255;
    return r;
  };
  __half* h1 = (__half*)carve((size_t)N_NODES * FTOT * 2);
  float* f1 = (float*)carve((size_t)N_NODES * 8 * 4);
  float* f2 = (float*)carve((size_t)N_NODES * 8 * 4);
  int* offsets = (int*)carve((size_t)(N_NODES + 1) * 4);
  int* cnt = (int*)carve((size_t)N_NODES * 4);
  int* rank = (int*)carve((size_t)E_TOT * 4);
  int* edst = (int*)carve((size_t)E_TOT * 4);
  int* bsum = (int*)carve((size_t)NB_SCAN * 4);
  short* Wt = (short*)carve((size_t)NHEADS * NFEAT * NHID * 2);
  float* hout = (float*)carve((size_t)N_NODES * 4);

  hipMemsetAsync(cnt, 0, (size_t)N_NODES * 4, stream);

  setup_kernel<<<512 + 6446, 256, 0, stream>>>(W, Wt, src, cnt, rank);
  gemm_mfma_kernel<<<782, 512, 0, stream>>>(x, Wt, a, h1, f1, f2);
  scan1_kernel<<<NB_SCAN, 256, 0, stream>>>(cnt, offsets, bsum);
  scan2_kernel<<<1, 256, 0, stream>>>(bsum, offsets);
  scan3_kernel<<<NB_SCAN, 256, 0, stream>>>(offsets, bsum);
  scatter_kernel<<<6446, 256, 0, stream>>>(src, dst, offsets, rank, edst);
  aggregate_kernel<<<N_NODES, 256, 0, stream>>>(h1, f1, f2, offsets, edst, W_out, hout);
  layer2_kernel<<<12500, 256, 0, stream>>>(offsets, edst, hout, a_out, out);
}

// Round 7
// 423.536 us; speedup vs baseline: 1.0965x; 1.0232x over previous
//
#include <hip/hip_runtime.h>
#include <hip/hip_bf16.h>
#include <hip/hip_fp16.h>
#include <math.h>

#define N_NODES 50000
#define NFEAT 256
#define NHID 64
#define NHEADS 8
#define FTOT 512
#define E_TOT 1650000
#define ALPHA 0.2f
#define NB_SCAN 196
#define ALDS 264  // LDS row stride in shorts (256 + 8 pad, keeps 16B align)

typedef short s16x4 __attribute__((ext_vector_type(4)));
typedef short s16x8 __attribute__((ext_vector_type(8)));
typedef float f32x4 __attribute__((ext_vector_type(4)));

__device__ __forceinline__ short f2bf(float f) {  // RNE f32->bf16
  unsigned u = __float_as_uint(f);
  unsigned r = u + 0x7fffu + ((u >> 16) & 1u);
  return (short)(r >> 16);
}

__device__ __forceinline__ float att_e(float f1v, float g) {
  float s = f1v + g;
  float lk = (s > 0.f) ? s : ALPHA * s;
  return expf(-lk);
}

__device__ __forceinline__ void fma8(float e, const uint4& u, float* acc) {
  const __half2* hp = reinterpret_cast<const __half2*>(&u);
#pragma unroll
  for (int k = 0; k < 4; ++k) {
    float2 f = __half22float2(hp[k]);
    acc[2 * k] += e * f.x;
    acc[2 * k + 1] += e * f.y;
  }
}

// blocks [0,512): W[h][k][j] fp32 -> Wt[h][j][k] bf16
// blocks [512,...): histogram of src + per-edge rank (atomicAdd return)
__global__ __launch_bounds__(256) void setup_kernel(
    const float* __restrict__ W, short* __restrict__ Wt,
    const int* __restrict__ src, int* __restrict__ cnt,
    int* __restrict__ rank) {
  int b = blockIdx.x, t = threadIdx.x;
  if (b < 512) {
    int idx = b * 256 + t;
    int h = idx >> 14, r = idx & 16383, k = r >> 6, j = r & 63;
    Wt[h * 16384 + j * 256 + k] = f2bf(W[idx]);
  } else {
    int i = (b - 512) * 256 + t;
    if (i < E_TOT) rank[i] = atomicAdd(&cnt[src[i]], 1);
  }
}

// h1[64 rows x 512 cols] per block via bf16 MFMA. 8 waves, wave w = head w.
// Whole 64x256 A-slice staged to LDS once (ONE barrier); B direct from L2.
// Fused epilogue writes f1/f2 (fp32) and h1 (fp16).
__global__ __launch_bounds__(512) void gemm_mfma_kernel(
    const float* __restrict__ x, const short* __restrict__ Wt,
    const float* __restrict__ a, __half* __restrict__ h1,
    float* __restrict__ f1, float* __restrict__ f2) {
  __shared__ __align__(16) short A_s[64 * ALDS];  // 33 KB
  int bm = blockIdx.x * 64;
  int t = threadIdx.x;
  int wid = t >> 6, l = t & 63;
  int lr = l & 15, lk = l >> 4;
  int arow = t >> 3, acol = (t & 7) * 4;  // thread covers cols acol+32*i
  const short* wbase = Wt + wid * 16384 + lr * 256 + lk * 8;
  int gr = bm + arow;
  // preload entire row slice (8 outstanding HBM loads), convert, store once
  float4 xr[8];
#pragma unroll
  for (int i = 0; i < 8; ++i) {
    if (gr < N_NODES)
      xr[i] = *reinterpret_cast<const float4*>(x + (size_t)gr * NFEAT + i * 32 + acol);
    else
      xr[i] = make_float4(0.f, 0.f, 0.f, 0.f);
  }
#pragma unroll
  for (int i = 0; i < 8; ++i) {
    s16x4 v;
    v[0] = f2bf(xr[i].x); v[1] = f2bf(xr[i].y);
    v[2] = f2bf(xr[i].z); v[3] = f2bf(xr[i].w);
    *reinterpret_cast<s16x4*>(&A_s[arow * ALDS + i * 32 + acol]) = v;
  }
  __syncthreads();
  f32x4 acc[4][4] = {};
  for (int k0 = 0; k0 < NFEAT; k0 += 32) {
    s16x8 bf[4];
#pragma unroll
    for (int nj = 0; nj < 4; ++nj)
      bf[nj] = *reinterpret_cast<const s16x8*>(wbase + nj * 16 * 256 + k0);
    s16x8 af[4];
#pragma unroll
    for (int mi = 0; mi < 4; ++mi)
      af[mi] = *reinterpret_cast<const s16x8*>(
          &A_s[(mi * 16 + lr) * ALDS + k0 + lk * 8]);
#pragma unroll
    for (int mi = 0; mi < 4; ++mi)
#pragma unroll
      for (int nj = 0; nj < 4; ++nj)
        acc[mi][nj] = __builtin_amdgcn_mfma_f32_16x16x32_bf16(
            af[mi], bf[nj], acc[mi][nj], 0, 0, 0);
  }
  // store h1 (fp16)
#pragma unroll
  for (int mi = 0; mi < 4; ++mi) {
#pragma unroll
    for (int nj = 0; nj < 4; ++nj) {
#pragma unroll
      for (int q = 0; q < 4; ++q) {
        int r = bm + mi * 16 + lk * 4 + q;
        if (r < N_NODES)
          h1[(size_t)r * FTOT + wid * 64 + nj * 16 + lr] =
              __float2half(acc[mi][nj][q]);
      }
    }
  }
  // fused f1/f2 for head=wid
  float a1v[4], a2v[4];
#pragma unroll
  for (int nj = 0; nj < 4; ++nj) {
    a1v[nj] = a[wid * 128 + nj * 16 + lr];
    a2v[nj] = a[wid * 128 + 64 + nj * 16 + lr];
  }
#pragma unroll
  for (int mi = 0; mi < 4; ++mi) {
#pragma unroll
    for (int q = 0; q < 4; ++q) {
      float p1 = 0.f, p2 = 0.f;
#pragma unroll
      for (int nj = 0; nj < 4; ++nj) {
        p1 += acc[mi][nj][q] * a1v[nj];
        p2 += acc[mi][nj][q] * a2v[nj];
      }
      p1 += __shfl_xor(p1, 1); p2 += __shfl_xor(p2, 1);
      p1 += __shfl_xor(p1, 2); p2 += __shfl_xor(p2, 2);
      p1 += __shfl_xor(p1, 4); p2 += __shfl_xor(p2, 4);
      p1 += __shfl_xor(p1, 8); p2 += __shfl_xor(p2, 8);
      int r = bm + mi * 16 + lk * 4 + q;
      if (lr == 0 && r < N_NODES) {
        f1[r * 8 + wid] = p1;
        f2[r * 8 + wid] = p2;
      }
    }
  }
}

__global__ __launch_bounds__(256) void scan1_kernel(const int* __restrict__ cnt,
                                                    int* __restrict__ offs,
                                                    int* __restrict__ bsum) {
  __shared__ int sh[256];
  int b = blockIdx.x, t = threadIdx.x, i = b * 256 + t;
  int v = (i < N_NODES) ? cnt[i] : 0;
  sh[t] = v;
  __syncthreads();
  for (int o = 1; o < 256; o <<= 1) {
    int u = (t >= o) ? sh[t - o] : 0;
    __syncthreads();
    sh[t] += u;
    __syncthreads();
  }
  if (i < N_NODES) offs[i] = sh[t] - v;
  if (t == 255) bsum[b] = sh[255];
}

__global__ __launch_bounds__(256) void scan2_kernel(int* __restrict__ bsum,
                                                    int* __restrict__ offs) {
  __shared__ int sh[256];
  int t = threadIdx.x;
  int v = (t < NB_SCAN) ? bsum[t] : 0;
  sh[t] = v;
  __syncthreads();
  for (int o = 1; o < 256; o <<= 1) {
    int u = (t >= o) ? sh[t - o] : 0;
    __syncthreads();
    sh[t] += u;
    __syncthreads();
  }
  if (t < NB_SCAN) bsum[t] = sh[t] - v;
  if (t == 255) offs[N_NODES] = sh[255];
}

__global__ __launch_bounds__(256) void scan3_kernel(int* __restrict__ offs,
                                                    const int* __restrict__ bsum) {
  int i = blockIdx.x * 256 + threadIdx.x;
  if (i < N_NODES) offs[i] += bsum[blockIdx.x];
}

// edst[offsets[s] + rank[i]] = dst[i]  (no atomics)
__global__ __launch_bounds__(256) void scatter_kernel(
    const int* __restrict__ src, const int* __restrict__ dst,
    const int* __restrict__ offsets, const int* __restrict__ rank,
    int* __restrict__ edst) {
  int i = blockIdx.x * 256 + threadIdx.x;
  if (i < E_TOT) {
    int s = src[i];
    edst[offsets[s] + rank[i]] = dst[i];
  }
}

// WAVE-per-node aggregation: no LDS, no barriers. Lane l owns features
// [8l, 8l+8) (head = l>>3); the 64 lanes cover the full 512-col row.
// rs is replicated within each 8-lane head group (no reduction needed).
// 4-deep edge pipeline inside the wave.
__global__ __launch_bounds__(256) void aggregate_kernel(
    const __half* __restrict__ h1, const float* __restrict__ f1,
    const float* __restrict__ f2, const int* __restrict__ offsets,
    const int* __restrict__ edst, const float* __restrict__ W_out,
    float* __restrict__ hout) {
  int n = blockIdx.x * 4 + (threadIdx.x >> 6);
  int l = threadIdx.x & 63;
  int head = l >> 3;
  int beg = offsets[n], end = offsets[n + 1];
  float f1v = f1[n * 8 + head];
  // W_out slice for this lane's 8 features (L1-resident after first touch)
  float4 w0 = *reinterpret_cast<const float4*>(W_out + l * 8);
  float4 w1 = *reinterpret_cast<const float4*>(W_out + l * 8 + 4);
  float acc[8] = {};
  float rs = 0.f;
  int j = beg;
  for (; j + 3 < end; j += 4) {
    int d0 = edst[j], d1 = edst[j + 1], d2 = edst[j + 2], d3 = edst[j + 3];
    uint4 u0 = *reinterpret_cast<const uint4*>(h1 + (size_t)d0 * FTOT + l * 8);
    uint4 u1 = *reinterpret_cast<const uint4*>(h1 + (size_t)d1 * FTOT + l * 8);
    uint4 u2 = *reinterpret_cast<const uint4*>(h1 + (size_t)d2 * FTOT + l * 8);
    uint4 u3 = *reinterpret_cast<const uint4*>(h1 + (size_t)d3 * FTOT + l * 8);
    float g0 = f2[d0 * 8 + head];
    float g1 = f2[d1 * 8 + head];
    float g2 = f2[d2 * 8 + head];
    float g3 = f2[d3 * 8 + head];
    float e0 = att_e(f1v, g0), e1 = att_e(f1v, g1);
    float e2 = att_e(f1v, g2), e3 = att_e(f1v, g3);
    rs += (e0 + e1) + (e2 + e3);
    fma8(e0, u0, acc);
    fma8(e1, u1, acc);
    fma8(e2, u2, acc);
    fma8(e3, u3, acc);
  }
  for (; j < end; ++j) {
    int d = edst[j];
    uint4 u = *reinterpret_cast<const uint4*>(h1 + (size_t)d * FTOT + l * 8);
    float e = att_e(f1v, f2[d * 8 + head]);
    rs += e;
    fma8(e, u, acc);
  }
  // epilogue: elu(acc/rs) dot W_out, all in-wave
  float inv = 1.f / rs;
  float v = 0.f;
  const float* wp = reinterpret_cast<const float*>(&w0);
#pragma unroll
  for (int k = 0; k < 8; ++k) {
    float o = acc[k] * inv;
    o = (o > 0.f) ? o : expm1f(o);
    float wk = (k < 4) ? wp[k] : reinterpret_cast<const float*>(&w1)[k - 4];
    v += o * wk;
  }
#pragma unroll
  for (int o = 32; o > 0; o >>= 1) v += __shfl_down(v, o);
  if (l == 0) hout[n] = v;
}

// layer-2 edge phase + elu + sigmoid. 4 nodes/block, one wave each.
__global__ __launch_bounds__(256) void layer2_kernel(
    const int* __restrict__ offsets, const int* __restrict__ edst,
    const float* __restrict__ hout, const float* __restrict__ a_out,
    float* __restrict__ out) {
  int n = blockIdx.x * 4 + (threadIdx.x >> 6);
  int l = threadIdx.x & 63;
  float a0 = a_out[0], a1 = a_out[1];
  int beg = offsets[n], end = offsets[n + 1];
  float f1v = hout[n] * a0;
  float rs = 0.f, num = 0.f;
  for (int j = beg + l; j < end; j += 64) {
    int d = edst[j];
    float hd = hout[d];
    float s = f1v + a1 * hd;
    float lk = (s > 0.f) ? s : ALPHA * s;
    float e = expf(-lk);
    rs += e;
    num += e * hd;
  }
#pragma unroll
  for (int o = 32; o > 0; o >>= 1) {
    rs += __shfl_down(rs, o);
    num += __shfl_down(num, o);
  }
  if (l == 0) {
    float o_ = num / rs;
    float el = (o_ > 0.f) ? o_ : expm1f(o_);
    out[n] = 1.f / (1.f + expf(-el));
  }
}

extern "C" void kernel_launch(void* const* d_in, const int* in_sizes, int n_in,
                              void* d_out, int out_size, void* d_ws, size_t ws_size,
                              hipStream_t stream) {
  const float* x = (const float*)d_in[0];
  const int* ei = (const int*)d_in[1];
  const float* W = (const float*)d_in[2];
  const float* a = (const float*)d_in[3];
  const float* W_out = (const float*)d_in[4];
  const float* a_out = (const float*)d_in[5];
  float* out = (float*)d_out;
  const int* src = ei;
  const int* dst = ei + E_TOT;

  char* p = (char*)d_ws;
  auto carve = [&](size_t bytes) {
    char* r = p;
    p += (bytes + 255) & ~(size_t)255;
    return r;
  };
  __half* h1 = (__half*)carve((size_t)N_NODES * FTOT * 2);
  float* f1 = (float*)carve((size_t)N_NODES * 8 * 4);
  float* f2 = (float*)carve((size_t)N_NODES * 8 * 4);
  int* offsets = (int*)carve((size_t)(N_NODES + 1) * 4);
  int* cnt = (int*)carve((size_t)N_NODES * 4);
  int* rank = (int*)carve((size_t)E_TOT * 4);
  int* edst = (int*)carve((size_t)E_TOT * 4);
  int* bsum = (int*)carve((size_t)NB_SCAN * 4);
  short* Wt = (short*)carve((size_t)NHEADS * NFEAT * NHID * 2);
  float* hout = (float*)carve((size_t)N_NODES * 4);

  hipMemsetAsync(cnt, 0, (size_t)N_NODES * 4, stream);

  setup_kernel<<<512 + 6446, 256, 0, stream>>>(W, Wt, src, cnt, rank);
  gemm_mfma_kernel<<<782, 512, 0, stream>>>(x, Wt, a, h1, f1, f2);
  scan1_kernel<<<NB_SCAN, 256, 0, stream>>>(cnt, offsets, bsum);
  scan2_kernel<<<1, 256, 0, stream>>>(bsum, offsets);
  scan3_kernel<<<NB_SCAN, 256, 0, stream>>>(offsets, bsum);
  scatter_kernel<<<6446, 256, 0, stream>>>(src, dst, offsets, rank, edst);
  aggregate_kernel<<<12500, 256, 0, stream>>>(h1, f1, f2, offsets, edst, W_out, hout);
  layer2_kernel<<<12500, 256, 0, stream>>>(offsets, edst, hout, a_out, out);
}

// Round 8
// 316.901 us; speedup vs baseline: 1.4655x; 1.3365x over previous
//
#include <hip/hip_runtime.h>
#include <hip/hip_bf16.h>
#include <hip/hip_fp16.h>
#include <math.h>

#define N_NODES 50000
#define NFEAT 256
#define NHID 64
#define NHEADS 8
#define FTOT 512
#define E_TOT 1650000
#define ALPHA 0.2f
#define NB_SCAN 196
#define ALDS 264  // LDS row stride in shorts (256 + 8 pad, keeps 16B align)

typedef short s16x4 __attribute__((ext_vector_type(4)));
typedef short s16x8 __attribute__((ext_vector_type(8)));
typedef float f32x4 __attribute__((ext_vector_type(4)));
typedef float f32x2 __attribute__((ext_vector_type(2)));

__device__ __forceinline__ short f2bf(float f) {  // RNE f32->bf16
  unsigned u = __float_as_uint(f);
  unsigned r = u + 0x7fffu + ((u >> 16) & 1u);
  return (short)(r >> 16);
}

__device__ __forceinline__ unsigned char f2fp8(float f) {  // RNE f32->e4m3
  return (unsigned char)(__builtin_amdgcn_cvt_pk_fp8_f32(f, 0.f, 0, false) & 0xff);
}

__device__ __forceinline__ float att_e(float f1v, float g) {
  float s = f1v + g;
  float lk = (s > 0.f) ? s : ALPHA * s;
  return expf(-lk);
}

// decode 8 fp8 (uint2) and accumulate e * h into acc[0..8)
__device__ __forceinline__ void fma8_fp8(float e, uint2 u, float* acc) {
  f32x2 p;
  p = __builtin_amdgcn_cvt_pk_f32_fp8(u.x, false);
  acc[0] += e * p[0]; acc[1] += e * p[1];
  p = __builtin_amdgcn_cvt_pk_f32_fp8(u.x, true);
  acc[2] += e * p[0]; acc[3] += e * p[1];
  p = __builtin_amdgcn_cvt_pk_f32_fp8(u.y, false);
  acc[4] += e * p[0]; acc[5] += e * p[1];
  p = __builtin_amdgcn_cvt_pk_f32_fp8(u.y, true);
  acc[6] += e * p[0]; acc[7] += e * p[1];
}

// blocks [0,512): W[h][k][j] fp32 -> Wt[h][j][k] bf16
// blocks [512,...): histogram of src + per-edge rank (atomicAdd return)
__global__ __launch_bounds__(256) void setup_kernel(
    const float* __restrict__ W, short* __restrict__ Wt,
    const int* __restrict__ src, int* __restrict__ cnt,
    int* __restrict__ rank) {
  int b = blockIdx.x, t = threadIdx.x;
  if (b < 512) {
    int idx = b * 256 + t;
    int h = idx >> 14, r = idx & 16383, k = r >> 6, j = r & 63;
    Wt[h * 16384 + j * 256 + k] = f2bf(W[idx]);
  } else {
    int i = (b - 512) * 256 + t;
    if (i < E_TOT) rank[i] = atomicAdd(&cnt[src[i]], 1);
  }
}

// h1[64 rows x 512 cols] per block via bf16 MFMA. 8 waves, wave w = head w.
// Whole 64x256 A-slice staged to LDS once (ONE barrier); B direct from L2.
// Fused epilogue writes f1/f2 (fp32) and h1 (fp8 e4m3).
__global__ __launch_bounds__(512) void gemm_mfma_kernel(
    const float* __restrict__ x, const short* __restrict__ Wt,
    const float* __restrict__ a, unsigned char* __restrict__ h1,
    float* __restrict__ f1, float* __restrict__ f2) {
  __shared__ __align__(16) short A_s[64 * ALDS];  // 33 KB
  int bm = blockIdx.x * 64;
  int t = threadIdx.x;
  int wid = t >> 6, l = t & 63;
  int lr = l & 15, lk = l >> 4;
  int arow = t >> 3, acol = (t & 7) * 4;  // thread covers cols acol+32*i
  const short* wbase = Wt + wid * 16384 + lr * 256 + lk * 8;
  int gr = bm + arow;
  // preload entire row slice (8 outstanding HBM loads), convert, store once
  float4 xr[8];
#pragma unroll
  for (int i = 0; i < 8; ++i) {
    if (gr < N_NODES)
      xr[i] = *reinterpret_cast<const float4*>(x + (size_t)gr * NFEAT + i * 32 + acol);
    else
      xr[i] = make_float4(0.f, 0.f, 0.f, 0.f);
  }
#pragma unroll
  for (int i = 0; i < 8; ++i) {
    s16x4 v;
    v[0] = f2bf(xr[i].x); v[1] = f2bf(xr[i].y);
    v[2] = f2bf(xr[i].z); v[3] = f2bf(xr[i].w);
    *reinterpret_cast<s16x4*>(&A_s[arow * ALDS + i * 32 + acol]) = v;
  }
  __syncthreads();
  f32x4 acc[4][4] = {};
  for (int k0 = 0; k0 < NFEAT; k0 += 32) {
    s16x8 bf[4];
#pragma unroll
    for (int nj = 0; nj < 4; ++nj)
      bf[nj] = *reinterpret_cast<const s16x8*>(wbase + nj * 16 * 256 + k0);
    s16x8 af[4];
#pragma unroll
    for (int mi = 0; mi < 4; ++mi)
      af[mi] = *reinterpret_cast<const s16x8*>(
          &A_s[(mi * 16 + lr) * ALDS + k0 + lk * 8]);
#pragma unroll
    for (int mi = 0; mi < 4; ++mi)
#pragma unroll
      for (int nj = 0; nj < 4; ++nj)
        acc[mi][nj] = __builtin_amdgcn_mfma_f32_16x16x32_bf16(
            af[mi], bf[nj], acc[mi][nj], 0, 0, 0);
  }
  // store h1 (fp8 e4m3)
#pragma unroll
  for (int mi = 0; mi < 4; ++mi) {
#pragma unroll
    for (int nj = 0; nj < 4; ++nj) {
#pragma unroll
      for (int q = 0; q < 4; ++q) {
        int r = bm + mi * 16 + lk * 4 + q;
        if (r < N_NODES)
          h1[(size_t)r * FTOT + wid * 64 + nj * 16 + lr] = f2fp8(acc[mi][nj][q]);
      }
    }
  }
  // fused f1/f2 for head=wid
  float a1v[4], a2v[4];
#pragma unroll
  for (int nj = 0; nj < 4; ++nj) {
    a1v[nj] = a[wid * 128 + nj * 16 + lr];
    a2v[nj] = a[wid * 128 + 64 + nj * 16 + lr];
  }
#pragma unroll
  for (int mi = 0; mi < 4; ++mi) {
#pragma unroll
    for (int q = 0; q < 4; ++q) {
      float p1 = 0.f, p2 = 0.f;
#pragma unroll
      for (int nj = 0; nj < 4; ++nj) {
        p1 += acc[mi][nj][q] * a1v[nj];
        p2 += acc[mi][nj][q] * a2v[nj];
      }
      p1 += __shfl_xor(p1, 1); p2 += __shfl_xor(p2, 1);
      p1 += __shfl_xor(p1, 2); p2 += __shfl_xor(p2, 2);
      p1 += __shfl_xor(p1, 4); p2 += __shfl_xor(p2, 4);
      p1 += __shfl_xor(p1, 8); p2 += __shfl_xor(p2, 8);
      int r = bm + mi * 16 + lk * 4 + q;
      if (lr == 0 && r < N_NODES) {
        f1[r * 8 + wid] = p1;
        f2[r * 8 + wid] = p2;
      }
    }
  }
}

__global__ __launch_bounds__(256) void scan1_kernel(const int* __restrict__ cnt,
                                                    int* __restrict__ offs,
                                                    int* __restrict__ bsum) {
  __shared__ int sh[256];
  int b = blockIdx.x, t = threadIdx.x, i = b * 256 + t;
  int v = (i < N_NODES) ? cnt[i] : 0;
  sh[t] = v;
  __syncthreads();
  for (int o = 1; o < 256; o <<= 1) {
    int u = (t >= o) ? sh[t - o] : 0;
    __syncthreads();
    sh[t] += u;
    __syncthreads();
  }
  if (i < N_NODES) offs[i] = sh[t] - v;
  if (t == 255) bsum[b] = sh[255];
}

__global__ __launch_bounds__(256) void scan2_kernel(int* __restrict__ bsum,
                                                    int* __restrict__ offs) {
  __shared__ int sh[256];
  int t = threadIdx.x;
  int v = (t < NB_SCAN) ? bsum[t] : 0;
  sh[t] = v;
  __syncthreads();
  for (int o = 1; o < 256; o <<= 1) {
    int u = (t >= o) ? sh[t - o] : 0;
    __syncthreads();
    sh[t] += u;
    __syncthreads();
  }
  if (t < NB_SCAN) bsum[t] = sh[t] - v;
  if (t == 255) offs[N_NODES] = sh[255];
}

__global__ __launch_bounds__(256) void scan3_kernel(int* __restrict__ offs,
                                                    const int* __restrict__ bsum) {
  int i = blockIdx.x * 256 + threadIdx.x;
  if (i < N_NODES) offs[i] += bsum[blockIdx.x];
}

// edst[offsets[s] + rank[i]] = dst[i]  (no atomics)
__global__ __launch_bounds__(256) void scatter_kernel(
    const int* __restrict__ src, const int* __restrict__ dst,
    const int* __restrict__ offsets, const int* __restrict__ rank,
    int* __restrict__ edst) {
  int i = blockIdx.x * 256 + threadIdx.x;
  if (i < E_TOT) {
    int s = src[i];
    edst[offsets[s] + rank[i]] = dst[i];
  }
}

// WAVE-per-node aggregation: no LDS, no barriers. Lane l owns features
// [8l, 8l+8) (head = l>>3); 64 lanes cover the full 512-col row (fp8: 8B/lane).
// rs is replicated within each 8-lane head group. 4-deep edge pipeline.
__global__ __launch_bounds__(256) void aggregate_kernel(
    const unsigned char* __restrict__ h1, const float* __restrict__ f1,
    const float* __restrict__ f2, const int* __restrict__ offsets,
    const int* __restrict__ edst, const float* __restrict__ W_out,
    float* __restrict__ hout) {
  int n = blockIdx.x * 4 + (threadIdx.x >> 6);
  int l = threadIdx.x & 63;
  int head = l >> 3;
  int beg = offsets[n], end = offsets[n + 1];
  float f1v = f1[n * 8 + head];
  float4 w0 = *reinterpret_cast<const float4*>(W_out + l * 8);
  float4 w1 = *reinterpret_cast<const float4*>(W_out + l * 8 + 4);
  float acc[8] = {};
  float rs = 0.f;
  int j = beg;
  for (; j + 3 < end; j += 4) {
    int d0 = edst[j], d1 = edst[j + 1], d2 = edst[j + 2], d3 = edst[j + 3];
    uint2 u0 = *reinterpret_cast<const uint2*>(h1 + (size_t)d0 * FTOT + l * 8);
    uint2 u1 = *reinterpret_cast<const uint2*>(h1 + (size_t)d1 * FTOT + l * 8);
    uint2 u2 = *reinterpret_cast<const uint2*>(h1 + (size_t)d2 * FTOT + l * 8);
    uint2 u3 = *reinterpret_cast<const uint2*>(h1 + (size_t)d3 * FTOT + l * 8);
    float g0 = f2[d0 * 8 + head];
    float g1 = f2[d1 * 8 + head];
    float g2 = f2[d2 * 8 + head];
    float g3 = f2[d3 * 8 + head];
    float e0 = att_e(f1v, g0), e1 = att_e(f1v, g1);
    float e2 = att_e(f1v, g2), e3 = att_e(f1v, g3);
    rs += (e0 + e1) + (e2 + e3);
    fma8_fp8(e0, u0, acc);
    fma8_fp8(e1, u1, acc);
    fma8_fp8(e2, u2, acc);
    fma8_fp8(e3, u3, acc);
  }
  for (; j < end; ++j) {
    int d = edst[j];
    uint2 u = *reinterpret_cast<const uint2*>(h1 + (size_t)d * FTOT + l * 8);
    float e = att_e(f1v, f2[d * 8 + head]);
    rs += e;
    fma8_fp8(e, u, acc);
  }
  // epilogue: elu(acc/rs) dot W_out, all in-wave
  float inv = 1.f / rs;
  float v = 0.f;
  const float* wp0 = reinterpret_cast<const float*>(&w0);
  const float* wp1 = reinterpret_cast<const float*>(&w1);
#pragma unroll
  for (int k = 0; k < 8; ++k) {
    float o = acc[k] * inv;
    o = (o > 0.f) ? o : expm1f(o);
    float wk = (k < 4) ? wp0[k] : wp1[k - 4];
    v += o * wk;
  }
#pragma unroll
  for (int o = 32; o > 0; o >>= 1) v += __shfl_down(v, o);
  if (l == 0) hout[n] = v;
}

// layer-2 edge phase + elu + sigmoid. 4 nodes/block, one wave each.
__global__ __launch_bounds__(256) void layer2_kernel(
    const int* __restrict__ offsets, const int* __restrict__ edst,
    const float* __restrict__ hout, const float* __restrict__ a_out,
    float* __restrict__ out) {
  int n = blockIdx.x * 4 + (threadIdx.x >> 6);
  int l = threadIdx.x & 63;
  float a0 = a_out[0], a1 = a_out[1];
  int beg = offsets[n], end = offsets[n + 1];
  float f1v = hout[n] * a0;
  float rs = 0.f, num = 0.f;
  for (int j = beg + l; j < end; j += 64) {
    int d = edst[j];
    float hd = hout[d];
    float s = f1v + a1 * hd;
    float lk = (s > 0.f) ? s : ALPHA * s;
    float e = expf(-lk);
    rs += e;
    num += e * hd;
  }
#pragma unroll
  for (int o = 32; o > 0; o >>= 1) {
    rs += __shfl_down(rs, o);
    num += __shfl_down(num, o);
  }
  if (l == 0) {
    float o_ = num / rs;
    float el = (o_ > 0.f) ? o_ : expm1f(o_);
    out[n] = 1.f / (1.f + expf(-el));
  }
}

extern "C" void kernel_launch(void* const* d_in, const int* in_sizes, int n_in,
                              void* d_out, int out_size, void* d_ws, size_t ws_size,
                              hipStream_t stream) {
  const float* x = (const float*)d_in[0];
  const int* ei = (const int*)d_in[1];
  const float* W = (const float*)d_in[2];
  const float* a = (const float*)d_in[3];
  const float* W_out = (const float*)d_in[4];
  const float* a_out = (const float*)d_in[5];
  float* out = (float*)d_out;
  const int* src = ei;
  const int* dst = ei + E_TOT;

  char* p = (char*)d_ws;
  auto carve = [&](size_t bytes) {
    char* r = p;
    p += (bytes + 255) & ~(size_t)255;
    return r;
  };
  unsigned char* h1 = (unsigned char*)carve((size_t)N_NODES * FTOT);
  float* f1 = (float*)carve((size_t)N_NODES * 8 * 4);
  float* f2 = (float*)carve((size_t)N_NODES * 8 * 4);
  int* offsets = (int*)carve((size_t)(N_NODES + 1) * 4);
  int* cnt = (int*)carve((size_t)N_NODES * 4);
  int* rank = (int*)carve((size_t)E_TOT * 4);
  int* edst = (int*)carve((size_t)E_TOT * 4);
  int* bsum = (int*)carve((size_t)NB_SCAN * 4);
  short* Wt = (short*)carve((size_t)NHEADS * NFEAT * NHID * 2);
  float* hout = (float*)carve((size_t)N_NODES * 4);

  hipMemsetAsync(cnt, 0, (size_t)N_NODES * 4, stream);

  setup_kernel<<<512 + 6446, 256, 0, stream>>>(W, Wt, src, cnt, rank);
  gemm_mfma_kernel<<<782, 512, 0, stream>>>(x, Wt, a, h1, f1, f2);
  scan1_kernel<<<NB_SCAN, 256, 0, stream>>>(cnt, offsets, bsum);
  scan2_kernel<<<1, 256, 0, stream>>>(bsum, offsets);
  scan3_kernel<<<NB_SCAN, 256, 0, stream>>>(offsets, bsum);
  scatter_kernel<<<6446, 256, 0, stream>>>(src, dst, offsets, rank, edst);
  aggregate_kernel<<<12500, 256, 0, stream>>>(h1, f1, f2, offsets, edst, W_out, hout);
  layer2_kernel<<<12500, 256, 0, stream>>>(offsets, edst, hout, a_out, out);
}

// Round 9
// 291.672 us; speedup vs baseline: 1.5922x; 1.0865x over previous
//
#include <hip/hip_runtime.h>
#include <hip/hip_bf16.h>
#include <hip/hip_fp16.h>
#include <math.h>

#define N_NODES 50000
#define NFEAT 256
#define NHID 64
#define NHEADS 8
#define FTOT 512
#define E_TOT 1650000
#define ALPHA 0.2f
#define NB_SCAN 196
#define ALDS 264  // LDS row stride in shorts (256 + 8 pad, keeps 16B align)
#define GEMM_BLKS 782
#define SCAT_BLKS 3223
#define LOG2E 1.442695040888963f

typedef short s16x4 __attribute__((ext_vector_type(4)));
typedef short s16x8 __attribute__((ext_vector_type(8)));
typedef float f32x4 __attribute__((ext_vector_type(4)));
typedef float f32x2 __attribute__((ext_vector_type(2)));

__device__ __forceinline__ short f2bf(float f) {  // RNE f32->bf16
  unsigned u = __float_as_uint(f);
  unsigned r = u + 0x7fffu + ((u >> 16) & 1u);
  return (short)(r >> 16);
}

__device__ __forceinline__ unsigned char f2fp8(float f) {  // RNE f32->e4m3
  return (unsigned char)(__builtin_amdgcn_cvt_pk_fp8_f32(f, 0.f, 0, false) & 0xff);
}

// e = exp(-leakyrelu(s)) with fast exp2: lrelu(s) = max(s, 0.2s)
__device__ __forceinline__ float att_e(float f1v, float g) {
  float s = f1v + g;
  float lk = fmaxf(s, ALPHA * s);
  return __builtin_amdgcn_exp2f(-LOG2E * lk);
}

// decode 8 fp8 (uint2), accumulate e*h into 4 packed-f32 accumulators
__device__ __forceinline__ void fma8_fp8(float e, uint2 u, f32x2* acc2) {
  f32x2 ev; ev[0] = e; ev[1] = e;
  acc2[0] += ev * __builtin_amdgcn_cvt_pk_f32_fp8(u.x, false);
  acc2[1] += ev * __builtin_amdgcn_cvt_pk_f32_fp8(u.x, true);
  acc2[2] += ev * __builtin_amdgcn_cvt_pk_f32_fp8(u.y, false);
  acc2[3] += ev * __builtin_amdgcn_cvt_pk_f32_fp8(u.y, true);
}

// blocks [0,512): W[h][k][j] fp32 -> Wt[h][j][k] bf16
// blocks [512,...): histogram of src + per-edge rank (atomicAdd return)
__global__ __launch_bounds__(256) void setup_kernel(
    const float* __restrict__ W, short* __restrict__ Wt,
    const int* __restrict__ src, int* __restrict__ cnt,
    int* __restrict__ rank) {
  int b = blockIdx.x, t = threadIdx.x;
  if (b < 512) {
    int idx = b * 256 + t;
    int h = idx >> 14, r = idx & 16383, k = r >> 6, j = r & 63;
    Wt[h * 16384 + j * 256 + k] = f2bf(W[idx]);
  } else {
    int i = (b - 512) * 256 + t;
    if (i < E_TOT) rank[i] = atomicAdd(&cnt[src[i]], 1);
  }
}

__global__ __launch_bounds__(256) void scan1_kernel(const int* __restrict__ cnt,
                                                    int* __restrict__ offs,
                                                    int* __restrict__ bsum) {
  __shared__ int sh[256];
  int b = blockIdx.x, t = threadIdx.x, i = b * 256 + t;
  int v = (i < N_NODES) ? cnt[i] : 0;
  sh[t] = v;
  __syncthreads();
  for (int o = 1; o < 256; o <<= 1) {
    int u = (t >= o) ? sh[t - o] : 0;
    __syncthreads();
    sh[t] += u;
    __syncthreads();
  }
  if (i < N_NODES) offs[i] = sh[t] - v;
  if (t == 255) bsum[b] = sh[255];
}

__global__ __launch_bounds__(256) void scan2_kernel(int* __restrict__ bsum,
                                                    int* __restrict__ offs) {
  __shared__ int sh[256];
  int t = threadIdx.x;
  int v = (t < NB_SCAN) ? bsum[t] : 0;
  sh[t] = v;
  __syncthreads();
  for (int o = 1; o < 256; o <<= 1) {
    int u = (t >= o) ? sh[t - o] : 0;
    __syncthreads();
    sh[t] += u;
    __syncthreads();
  }
  if (t < NB_SCAN) bsum[t] = sh[t] - v;
  if (t == 255) offs[N_NODES] = sh[255];
}

__global__ __launch_bounds__(256) void scan3_kernel(int* __restrict__ offs,
                                                    const int* __restrict__ bsum) {
  int i = blockIdx.x * 256 + threadIdx.x;
  if (i < N_NODES) offs[i] += bsum[blockIdx.x];
}

// blocks [0,GEMM_BLKS): h1 GEMM via bf16 MFMA (8 waves, wave = head).
// blocks [GEMM_BLKS,...): edst scatter (independent work, overlapped).
__global__ __launch_bounds__(512) void gemm_scatter_kernel(
    const float* __restrict__ x, const short* __restrict__ Wt,
    const float* __restrict__ a, unsigned char* __restrict__ h1,
    float* __restrict__ f1, float* __restrict__ f2,
    const int* __restrict__ src, const int* __restrict__ dst,
    const int* __restrict__ offsets, const int* __restrict__ rank,
    int* __restrict__ edst) {
  if (blockIdx.x >= GEMM_BLKS) {
    int i = (blockIdx.x - GEMM_BLKS) * 512 + threadIdx.x;
    if (i < E_TOT) edst[offsets[src[i]] + rank[i]] = dst[i];
    return;
  }
  __shared__ __align__(16) short A_s[64 * ALDS];  // 33 KB
  int bm = blockIdx.x * 64;
  int t = threadIdx.x;
  int wid = t >> 6, l = t & 63;
  int lr = l & 15, lk = l >> 4;
  int arow = t >> 3, acol = (t & 7) * 4;  // thread covers cols acol+32*i
  const short* wbase = Wt + wid * 16384 + lr * 256 + lk * 8;
  int gr = bm + arow;
  float4 xr[8];
#pragma unroll
  for (int i = 0; i < 8; ++i) {
    if (gr < N_NODES)
      xr[i] = *reinterpret_cast<const float4*>(x + (size_t)gr * NFEAT + i * 32 + acol);
    else
      xr[i] = make_float4(0.f, 0.f, 0.f, 0.f);
  }
#pragma unroll
  for (int i = 0; i < 8; ++i) {
    s16x4 v;
    v[0] = f2bf(xr[i].x); v[1] = f2bf(xr[i].y);
    v[2] = f2bf(xr[i].z); v[3] = f2bf(xr[i].w);
    *reinterpret_cast<s16x4*>(&A_s[arow * ALDS + i * 32 + acol]) = v;
  }
  __syncthreads();
  f32x4 acc[4][4] = {};
  for (int k0 = 0; k0 < NFEAT; k0 += 32) {
    s16x8 bf[4];
#pragma unroll
    for (int nj = 0; nj < 4; ++nj)
      bf[nj] = *reinterpret_cast<const s16x8*>(wbase + nj * 16 * 256 + k0);
    s16x8 af[4];
#pragma unroll
    for (int mi = 0; mi < 4; ++mi)
      af[mi] = *reinterpret_cast<const s16x8*>(
          &A_s[(mi * 16 + lr) * ALDS + k0 + lk * 8]);
#pragma unroll
    for (int mi = 0; mi < 4; ++mi)
#pragma unroll
      for (int nj = 0; nj < 4; ++nj)
        acc[mi][nj] = __builtin_amdgcn_mfma_f32_16x16x32_bf16(
            af[mi], bf[nj], acc[mi][nj], 0, 0, 0);
  }
  // store h1 (fp8 e4m3)
#pragma unroll
  for (int mi = 0; mi < 4; ++mi) {
#pragma unroll
    for (int nj = 0; nj < 4; ++nj) {
#pragma unroll
      for (int q = 0; q < 4; ++q) {
        int r = bm + mi * 16 + lk * 4 + q;
        if (r < N_NODES)
          h1[(size_t)r * FTOT + wid * 64 + nj * 16 + lr] = f2fp8(acc[mi][nj][q]);
      }
    }
  }
  // fused f1/f2 for head=wid
  float a1v[4], a2v[4];
#pragma unroll
  for (int nj = 0; nj < 4; ++nj) {
    a1v[nj] = a[wid * 128 + nj * 16 + lr];
    a2v[nj] = a[wid * 128 + 64 + nj * 16 + lr];
  }
#pragma unroll
  for (int mi = 0; mi < 4; ++mi) {
#pragma unroll
    for (int q = 0; q < 4; ++q) {
      float p1 = 0.f, p2 = 0.f;
#pragma unroll
      for (int nj = 0; nj < 4; ++nj) {
        p1 += acc[mi][nj][q] * a1v[nj];
        p2 += acc[mi][nj][q] * a2v[nj];
      }
      p1 += __shfl_xor(p1, 1); p2 += __shfl_xor(p2, 1);
      p1 += __shfl_xor(p1, 2); p2 += __shfl_xor(p2, 2);
      p1 += __shfl_xor(p1, 4); p2 += __shfl_xor(p2, 4);
      p1 += __shfl_xor(p1, 8); p2 += __shfl_xor(p2, 8);
      int r = bm + mi * 16 + lk * 4 + q;
      if (lr == 0 && r < N_NODES) {
        f1[r * 8 + wid] = p1;
        f2[r * 8 + wid] = p2;
      }
    }
  }
}

// WAVE-per-node aggregation. Wave index forced to SGPR (readfirstlane) so
// n/beg/end/edst loads run on the scalar pipe; h1/f2 use saddr+voffset.
// Lane l owns features [8l,8l+8) (head=l>>3); f32x2 accs feed v_pk_fma_f32.
__global__ __launch_bounds__(256) void aggregate_kernel(
    const unsigned char* __restrict__ h1, const float* __restrict__ f1,
    const float* __restrict__ f2, const int* __restrict__ offsets,
    const int* __restrict__ edst, const float* __restrict__ W_out,
    float* __restrict__ hout) {
  int wv = __builtin_amdgcn_readfirstlane(threadIdx.x >> 6);
  int n = blockIdx.x * 4 + wv;
  int l = threadIdx.x & 63;
  int head = l >> 3;
  int beg = offsets[n], end = offsets[n + 1];
  float f1v = f1[n * 8 + head];
  f32x2 acc2[4] = {};
  float rs = 0.f;
  int j = beg;
  for (; j + 3 < end; j += 4) {
    int d0 = edst[j], d1 = edst[j + 1], d2 = edst[j + 2], d3 = edst[j + 3];
    uint2 u0 = *reinterpret_cast<const uint2*>(h1 + (size_t)d0 * FTOT + l * 8);
    uint2 u1 = *reinterpret_cast<const uint2*>(h1 + (size_t)d1 * FTOT + l * 8);
    uint2 u2 = *reinterpret_cast<const uint2*>(h1 + (size_t)d2 * FTOT + l * 8);
    uint2 u3 = *reinterpret_cast<const uint2*>(h1 + (size_t)d3 * FTOT + l * 8);
    float g0 = f2[d0 * 8 + head];
    float g1 = f2[d1 * 8 + head];
    float g2 = f2[d2 * 8 + head];
    float g3 = f2[d3 * 8 + head];
    float e0 = att_e(f1v, g0), e1 = att_e(f1v, g1);
    float e2 = att_e(f1v, g2), e3 = att_e(f1v, g3);
    rs += (e0 + e1) + (e2 + e3);
    fma8_fp8(e0, u0, acc2);
    fma8_fp8(e1, u1, acc2);
    fma8_fp8(e2, u2, acc2);
    fma8_fp8(e3, u3, acc2);
  }
  for (; j < end; ++j) {
    int d = edst[j];
    uint2 u = *reinterpret_cast<const uint2*>(h1 + (size_t)d * FTOT + l * 8);
    float e = att_e(f1v, f2[d * 8 + head]);
    rs += e;
    fma8_fp8(e, u, acc2);
  }
  // epilogue: elu(acc/rs) dot W_out, all in-wave
  float inv = 1.f / rs;
  float v = 0.f;
  const float* wop = W_out + l * 8;
#pragma unroll
  for (int k = 0; k < 4; ++k) {
#pragma unroll
    for (int q = 0; q < 2; ++q) {
      float o = acc2[k][q] * inv;
      o = (o > 0.f) ? o : expm1f(o);
      v += o * wop[k * 2 + q];
    }
  }
#pragma unroll
  for (int o = 32; o > 0; o >>= 1) v += __shfl_down(v, o);
  if (l == 0) hout[n] = v;
}

// layer-2 edge phase + elu + sigmoid. 4 nodes/block, one wave each.
__global__ __launch_bounds__(256) void layer2_kernel(
    const int* __restrict__ offsets, const int* __restrict__ edst,
    const float* __restrict__ hout, const float* __restrict__ a_out,
    float* __restrict__ out) {
  int wv = __builtin_amdgcn_readfirstlane(threadIdx.x >> 6);
  int n = blockIdx.x * 4 + wv;
  int l = threadIdx.x & 63;
  float a0 = a_out[0], a1 = a_out[1];
  int beg = offsets[n], end = offsets[n + 1];
  float f1v = hout[n] * a0;
  float rs = 0.f, num = 0.f;
  for (int j = beg + l; j < end; j += 64) {
    int d = edst[j];
    float hd = hout[d];
    float s = f1v + a1 * hd;
    float lk = fmaxf(s, ALPHA * s);
    float e = __builtin_amdgcn_exp2f(-LOG2E * lk);
    rs += e;
    num += e * hd;
  }
#pragma unroll
  for (int o = 32; o > 0; o >>= 1) {
    rs += __shfl_down(rs, o);
    num += __shfl_down(num, o);
  }
  if (l == 0) {
    float o_ = num / rs;
    float el = (o_ > 0.f) ? o_ : expm1f(o_);
    out[n] = 1.f / (1.f + __builtin_amdgcn_exp2f(-LOG2E * el));
  }
}

extern "C" void kernel_launch(void* const* d_in, const int* in_sizes, int n_in,
                              void* d_out, int out_size, void* d_ws, size_t ws_size,
                              hipStream_t stream) {
  const float* x = (const float*)d_in[0];
  const int* ei = (const int*)d_in[1];
  const float* W = (const float*)d_in[2];
  const float* a = (const float*)d_in[3];
  const float* W_out = (const float*)d_in[4];
  const float* a_out = (const float*)d_in[5];
  float* out = (float*)d_out;
  const int* src = ei;
  const int* dst = ei + E_TOT;

  char* p = (char*)d_ws;
  auto carve = [&](size_t bytes) {
    char* r = p;
    p += (bytes + 255) & ~(size_t)255;
    return r;
  };
  unsigned char* h1 = (unsigned char*)carve((size_t)N_NODES * FTOT);
  float* f1 = (float*)carve((size_t)N_NODES * 8 * 4);
  float* f2 = (float*)carve((size_t)N_NODES * 8 * 4);
  int* offsets = (int*)carve((size_t)(N_NODES + 1) * 4);
  int* cnt = (int*)carve((size_t)N_NODES * 4);
  int* rank = (int*)carve((size_t)E_TOT * 4);
  int* edst = (int*)carve((size_t)E_TOT * 4);
  int* bsum = (int*)carve((size_t)NB_SCAN * 4);
  short* Wt = (short*)carve((size_t)NHEADS * NFEAT * NHID * 2);
  float* hout = (float*)carve((size_t)N_NODES * 4);

  hipMemsetAsync(cnt, 0, (size_t)N_NODES * 4, stream);

  setup_kernel<<<512 + 6446, 256, 0, stream>>>(W, Wt, src, cnt, rank);
  scan1_kernel<<<NB_SCAN, 256, 0, stream>>>(cnt, offsets, bsum);
  scan2_kernel<<<1, 256, 0, stream>>>(bsum, offsets);
  scan3_kernel<<<NB_SCAN, 256, 0, stream>>>(offsets, bsum);
  gemm_scatter_kernel<<<GEMM_BLKS + SCAT_BLKS, 512, 0, stream>>>(
      x, Wt, a, h1, f1, f2, src, dst, offsets, rank, edst);
  aggregate_kernel<<<12500, 256, 0, stream>>>(h1, f1, f2, offsets, edst, W_out, hout);
  layer2_kernel<<<12500, 256, 0, stream>>>(offsets, edst, hout, a_out, out);
}

// Round 10
// 291.397 us; speedup vs baseline: 1.5937x; 1.0009x over previous
//
#include <hip/hip_runtime.h>
#include <hip/hip_bf16.h>
#include <hip/hip_fp16.h>
#include <math.h>

#define N_NODES 50000
#define NFEAT 256
#define NHID 64
#define NHEADS 8
#define FTOT 512
#define E_TOT 1650000
#define ALPHA 0.2f
#define NB_SCAN 196
#define ALDS 264  // LDS row stride in shorts (256 + 8 pad, keeps 16B align)
#define GEMM_BLKS 782
#define SCAT_BLKS 3223
#define LOG2E 1.442695040888963f

typedef short s16x4 __attribute__((ext_vector_type(4)));
typedef short s16x8 __attribute__((ext_vector_type(8)));
typedef float f32x4 __attribute__((ext_vector_type(4)));
typedef float f32x2 __attribute__((ext_vector_type(2)));

__device__ __forceinline__ short f2bf(float f) {  // RNE f32->bf16
  unsigned u = __float_as_uint(f);
  unsigned r = u + 0x7fffu + ((u >> 16) & 1u);
  return (short)(r >> 16);
}

__device__ __forceinline__ unsigned char f2fp8(float f) {  // RNE f32->e4m3
  return (unsigned char)(__builtin_amdgcn_cvt_pk_fp8_f32(f, 0.f, 0, false) & 0xff);
}

// decode 8 fp8 (uint2), accumulate e*h into 4 packed-f32 accumulators
__device__ __forceinline__ void fma8_fp8(float e, uint2 u, f32x2* acc2) {
  f32x2 ev; ev[0] = e; ev[1] = e;
  acc2[0] += ev * __builtin_amdgcn_cvt_pk_f32_fp8(u.x, false);
  acc2[1] += ev * __builtin_amdgcn_cvt_pk_f32_fp8(u.x, true);
  acc2[2] += ev * __builtin_amdgcn_cvt_pk_f32_fp8(u.y, false);
  acc2[3] += ev * __builtin_amdgcn_cvt_pk_f32_fp8(u.y, true);
}

// blocks [0,512): W[h][k][j] fp32 -> Wt[h][j][k] bf16
// blocks [512,...): histogram of src + per-edge rank (atomicAdd return)
__global__ __launch_bounds__(256) void setup_kernel(
    const float* __restrict__ W, short* __restrict__ Wt,
    const int* __restrict__ src, int* __restrict__ cnt,
    int* __restrict__ rank) {
  int b = blockIdx.x, t = threadIdx.x;
  if (b < 512) {
    int idx = b * 256 + t;
    int h = idx >> 14, r = idx & 16383, k = r >> 6, j = r & 63;
    Wt[h * 16384 + j * 256 + k] = f2bf(W[idx]);
  } else {
    int i = (b - 512) * 256 + t;
    if (i < E_TOT) rank[i] = atomicAdd(&cnt[src[i]], 1);
  }
}

__global__ __launch_bounds__(256) void scan1_kernel(const int* __restrict__ cnt,
                                                    int* __restrict__ offs,
                                                    int* __restrict__ bsum) {
  __shared__ int sh[256];
  int b = blockIdx.x, t = threadIdx.x, i = b * 256 + t;
  int v = (i < N_NODES) ? cnt[i] : 0;
  sh[t] = v;
  __syncthreads();
  for (int o = 1; o < 256; o <<= 1) {
    int u = (t >= o) ? sh[t - o] : 0;
    __syncthreads();
    sh[t] += u;
    __syncthreads();
  }
  if (i < N_NODES) offs[i] = sh[t] - v;
  if (t == 255) bsum[b] = sh[255];
}

// merged scan2+scan3: every block prefixes the 196 block sums in LDS,
// then adds its own exclusive base to its offs slice.
__global__ __launch_bounds__(256) void scan23_kernel(
    const int* __restrict__ bsum, int* __restrict__ offs) {
  __shared__ int sh[256];
  int b = blockIdx.x, t = threadIdx.x;
  int v = (t < NB_SCAN) ? bsum[t] : 0;
  sh[t] = v;
  __syncthreads();
  for (int o = 1; o < 256; o <<= 1) {
    int u = (t >= o) ? sh[t - o] : 0;
    __syncthreads();
    sh[t] += u;
    __syncthreads();
  }
  int base = (b > 0) ? sh[b - 1] : 0;
  int i = b * 256 + t;
  if (i < N_NODES) offs[i] += base;
  if (b == 0 && t == 0) offs[N_NODES] = sh[NB_SCAN - 1];
}

// blocks [0,GEMM_BLKS): h1 GEMM via bf16 MFMA (8 waves, wave = head).
// blocks [GEMM_BLKS,...): edst scatter (independent work, overlapped).
__global__ __launch_bounds__(512) void gemm_scatter_kernel(
    const float* __restrict__ x, const short* __restrict__ Wt,
    const float* __restrict__ a, unsigned char* __restrict__ h1,
    float* __restrict__ f1, float* __restrict__ f2,
    const int* __restrict__ src, const int* __restrict__ dst,
    const int* __restrict__ offsets, const int* __restrict__ rank,
    int* __restrict__ edst) {
  if (blockIdx.x >= GEMM_BLKS) {
    int i = (blockIdx.x - GEMM_BLKS) * 512 + threadIdx.x;
    if (i < E_TOT) edst[offsets[src[i]] + rank[i]] = dst[i];
    return;
  }
  __shared__ __align__(16) short A_s[64 * ALDS];  // 33 KB
  int bm = blockIdx.x * 64;
  int t = threadIdx.x;
  int wid = t >> 6, l = t & 63;
  int lr = l & 15, lk = l >> 4;
  int arow = t >> 3, acol = (t & 7) * 4;  // thread covers cols acol+32*i
  const short* wbase = Wt + wid * 16384 + lr * 256 + lk * 8;
  int gr = bm + arow;
  float4 xr[8];
#pragma unroll
  for (int i = 0; i < 8; ++i) {
    if (gr < N_NODES)
      xr[i] = *reinterpret_cast<const float4*>(x + (size_t)gr * NFEAT + i * 32 + acol);
    else
      xr[i] = make_float4(0.f, 0.f, 0.f, 0.f);
  }
#pragma unroll
  for (int i = 0; i < 8; ++i) {
    s16x4 v;
    v[0] = f2bf(xr[i].x); v[1] = f2bf(xr[i].y);
    v[2] = f2bf(xr[i].z); v[3] = f2bf(xr[i].w);
    *reinterpret_cast<s16x4*>(&A_s[arow * ALDS + i * 32 + acol]) = v;
  }
  __syncthreads();
  f32x4 acc[4][4] = {};
  for (int k0 = 0; k0 < NFEAT; k0 += 32) {
    s16x8 bf[4];
#pragma unroll
    for (int nj = 0; nj < 4; ++nj)
      bf[nj] = *reinterpret_cast<const s16x8*>(wbase + nj * 16 * 256 + k0);
    s16x8 af[4];
#pragma unroll
    for (int mi = 0; mi < 4; ++mi)
      af[mi] = *reinterpret_cast<const s16x8*>(
          &A_s[(mi * 16 + lr) * ALDS + k0 + lk * 8]);
#pragma unroll
    for (int mi = 0; mi < 4; ++mi)
#pragma unroll
      for (int nj = 0; nj < 4; ++nj)
        acc[mi][nj] = __builtin_amdgcn_mfma_f32_16x16x32_bf16(
            af[mi], bf[nj], acc[mi][nj], 0, 0, 0);
  }
  // store h1 (fp8 e4m3)
#pragma unroll
  for (int mi = 0; mi < 4; ++mi) {
#pragma unroll
    for (int nj = 0; nj < 4; ++nj) {
#pragma unroll
      for (int q = 0; q < 4; ++q) {
        int r = bm + mi * 16 + lk * 4 + q;
        if (r < N_NODES)
          h1[(size_t)r * FTOT + wid * 64 + nj * 16 + lr] = f2fp8(acc[mi][nj][q]);
      }
    }
  }
  // fused f1/f2 for head=wid
  float a1v[4], a2v[4];
#pragma unroll
  for (int nj = 0; nj < 4; ++nj) {
    a1v[nj] = a[wid * 128 + nj * 16 + lr];
    a2v[nj] = a[wid * 128 + 64 + nj * 16 + lr];
  }
#pragma unroll
  for (int mi = 0; mi < 4; ++mi) {
#pragma unroll
    for (int q = 0; q < 4; ++q) {
      float p1 = 0.f, p2 = 0.f;
#pragma unroll
      for (int nj = 0; nj < 4; ++nj) {
        p1 += acc[mi][nj][q] * a1v[nj];
        p2 += acc[mi][nj][q] * a2v[nj];
      }
      p1 += __shfl_xor(p1, 1); p2 += __shfl_xor(p2, 1);
      p1 += __shfl_xor(p1, 2); p2 += __shfl_xor(p2, 2);
      p1 += __shfl_xor(p1, 4); p2 += __shfl_xor(p2, 4);
      p1 += __shfl_xor(p1, 8); p2 += __shfl_xor(p2, 8);
      int r = bm + mi * 16 + lk * 4 + q;
      if (lr == 0 && r < N_NODES) {
        f1[r * 8 + wid] = p1;
        f2[r * 8 + wid] = p2;
      }
    }
  }
}

// WAVE-per-node aggregation, 8-deep gather pipeline (fp8 rows: 8B/lane).
// e = exp2(min(cs, alpha*cs)) with cs = -log2e*(f1+f2)  [exact algebra].
__global__ __launch_bounds__(256) void aggregate_kernel(
    const unsigned char* __restrict__ h1, const float* __restrict__ f1,
    const float* __restrict__ f2, const int* __restrict__ offsets,
    const int* __restrict__ edst, const float* __restrict__ W_out,
    float* __restrict__ hout) {
  int wv = __builtin_amdgcn_readfirstlane(threadIdx.x >> 6);
  int n = blockIdx.x * 4 + wv;
  int l = threadIdx.x & 63;
  int head = l >> 3;
  int beg = offsets[n], end = offsets[n + 1];
  float F = -LOG2E * f1[n * 8 + head];
  f32x2 acc2[4] = {};
  float rs = 0.f;
  int j = beg;
  for (; j + 7 < end; j += 8) {
    int dd[8];
#pragma unroll
    for (int k = 0; k < 8; ++k) dd[k] = edst[j + k];
    uint2 uu[8];
#pragma unroll
    for (int k = 0; k < 8; ++k)
      uu[k] = *reinterpret_cast<const uint2*>(h1 + (size_t)dd[k] * FTOT + l * 8);
    float gg[8];
#pragma unroll
    for (int k = 0; k < 8; ++k) gg[k] = f2[dd[k] * 8 + head];
#pragma unroll
    for (int k = 0; k < 8; ++k) {
      float cs = fmaf(-LOG2E, gg[k], F);
      float e = __builtin_amdgcn_exp2f(fminf(cs, ALPHA * cs));
      rs += e;
      fma8_fp8(e, uu[k], acc2);
    }
  }
  for (; j < end; ++j) {
    int d = edst[j];
    uint2 u = *reinterpret_cast<const uint2*>(h1 + (size_t)d * FTOT + l * 8);
    float cs = fmaf(-LOG2E, f2[d * 8 + head], F);
    float e = __builtin_amdgcn_exp2f(fminf(cs, ALPHA * cs));
    rs += e;
    fma8_fp8(e, u, acc2);
  }
  // epilogue: elu(acc/rs) dot W_out, all in-wave
  float inv = 1.f / rs;
  float v = 0.f;
  const float* wop = W_out + l * 8;
#pragma unroll
  for (int k = 0; k < 4; ++k) {
#pragma unroll
    for (int q = 0; q < 2; ++q) {
      float o = acc2[k][q] * inv;
      o = (o > 0.f) ? o : expm1f(o);
      v += o * wop[k * 2 + q];
    }
  }
#pragma unroll
  for (int o = 32; o > 0; o >>= 1) v += __shfl_down(v, o);
  if (l == 0) hout[n] = v;
}

// layer-2 edge phase + elu + sigmoid. 4 nodes/block, one wave each.
__global__ __launch_bounds__(256) void layer2_kernel(
    const int* __restrict__ offsets, const int* __restrict__ edst,
    const float* __restrict__ hout, const float* __restrict__ a_out,
    float* __restrict__ out) {
  int wv = __builtin_amdgcn_readfirstlane(threadIdx.x >> 6);
  int n = blockIdx.x * 4 + wv;
  int l = threadIdx.x & 63;
  float a0 = a_out[0], a1 = a_out[1];
  int beg = offsets[n], end = offsets[n + 1];
  float f1v = hout[n] * a0;
  float rs = 0.f, num = 0.f;
  for (int j = beg + l; j < end; j += 64) {
    int d = edst[j];
    float hd = hout[d];
    float s = f1v + a1 * hd;
    float lk = fmaxf(s, ALPHA * s);
    float e = __builtin_amdgcn_exp2f(-LOG2E * lk);
    rs += e;
    num += e * hd;
  }
#pragma unroll
  for (int o = 32; o > 0; o >>= 1) {
    rs += __shfl_down(rs, o);
    num += __shfl_down(num, o);
  }
  if (l == 0) {
    float o_ = num / rs;
    float el = (o_ > 0.f) ? o_ : expm1f(o_);
    out[n] = 1.f / (1.f + __builtin_amdgcn_exp2f(-LOG2E * el));
  }
}

extern "C" void kernel_launch(void* const* d_in, const int* in_sizes, int n_in,
                              void* d_out, int out_size, void* d_ws, size_t ws_size,
                              hipStream_t stream) {
  const float* x = (const float*)d_in[0];
  const int* ei = (const int*)d_in[1];
  const float* W = (const float*)d_in[2];
  const float* a = (const float*)d_in[3];
  const float* W_out = (const float*)d_in[4];
  const float* a_out = (const float*)d_in[5];
  float* out = (float*)d_out;
  const int* src = ei;
  const int* dst = ei + E_TOT;

  char* p = (char*)d_ws;
  auto carve = [&](size_t bytes) {
    char* r = p;
    p += (bytes + 255) & ~(size_t)255;
    return r;
  };
  unsigned char* h1 = (unsigned char*)carve((size_t)N_NODES * FTOT);
  float* f1 = (float*)carve((size_t)N_NODES * 8 * 4);
  float* f2 = (float*)carve((size_t)N_NODES * 8 * 4);
  int* offsets = (int*)carve((size_t)(N_NODES + 1) * 4);
  int* cnt = (int*)carve((size_t)N_NODES * 4);
  int* rank = (int*)carve((size_t)E_TOT * 4);
  int* edst = (int*)carve((size_t)E_TOT * 4);
  int* bsum = (int*)carve((size_t)NB_SCAN * 4);
  short* Wt = (short*)carve((size_t)NHEADS * NFEAT * NHID * 2);
  float* hout = (float*)carve((size_t)N_NODES * 4);

  hipMemsetAsync(cnt, 0, (size_t)N_NODES * 4, stream);

  setup_kernel<<<512 + 6446, 256, 0, stream>>>(W, Wt, src, cnt, rank);
  scan1_kernel<<<NB_SCAN, 256, 0, stream>>>(cnt, offsets, bsum);
  scan23_kernel<<<NB_SCAN, 256, 0, stream>>>(bsum, offsets);
  gemm_scatter_kernel<<<GEMM_BLKS + SCAT_BLKS, 512, 0, stream>>>(
      x, Wt, a, h1, f1, f2, src, dst, offsets, rank, edst);
  aggregate_kernel<<<12500, 256, 0, stream>>>(h1, f1, f2, offsets, edst, W_out, hout);
  layer2_kernel<<<12500, 256, 0, stream>>>(offsets, edst, hout, a_out, out);
}